// Round 1
// baseline (156.036 us; speedup 1.0000x reference)
//
#include <hip/hip_runtime.h>
#include <math.h>

// Problem constants
#define B_   4
#define N_   1024
#define K_   520
#define C1   64
#define C2   128
#define C3   1024
#define NROWS (B_*N_)                 // 4096
#define CNT1  ((float)(B_*N_*K_))     // 2129920
#define CNT2  ((float)(B_*N_))        // 4096
#define EPS_  1e-5f

// Workspace layout (float offsets). Total = 2,621,824 floats ~= 10.5 MB.
#define OFF_SUMS1   0                         // 128  (64 sum, 64 sumsq)
#define OFF_SUMS2   128                       // 256  (128 sum, 128 sumsq)
#define OFF_PART1   384                       // 512*128
#define OFF_PART2   (OFF_PART1 + 512*128)     // 256*256
#define OFF_M1      (OFF_PART2 + 256*256)     // 4096*64   max_k h1, layout [row][c]
#define OFF_H2      (OFF_M1 + 4096*64)        // 4096*128  layout [col][o]
#define OFF_W3T     (OFF_H2 + 4096*128)       // 128*1024  w3 transposed [i][o]
#define OFF_PSUM    (OFF_W3T + 128*1024)      // 512*1024  per-tile channel sums of h3
#define OFF_PSQ     (OFF_PSUM + 512*1024)     // 512*1024
#define OFF_PMAX    (OFF_PSQ + 512*1024)      // 512*1024

// ---------------- K0: transpose w3 (1024x128) -> w3t (128x1024) ----------------
__global__ __launch_bounds__(256) void k0_w3t(const float* __restrict__ w3,
                                              float* __restrict__ ws) {
    float* w3t = ws + OFF_W3T;
    int idx = blockIdx.x * 256 + threadIdx.x;      // 0..131071
    int i = idx >> 10, o = idx & 1023;
    w3t[idx] = w3[o * 128 + i];                    // coalesced writes
}

// ---------------- K1: fused conv1 (6->64) + BN1 stats + max over K --------------
// Each block grid-strides over rows (b,n). 4 waves: wave wv handles k-chunk
// [wv*132, +132) (last: 124). Thread t: channel c = t&63.
// h = w[c][0..2]*ips + base, base folds the (x) half of feat and bias.
__global__ __launch_bounds__(256) void k1_feat(const float* __restrict__ x,
                                               const float* __restrict__ ips,
                                               const float* __restrict__ w1,
                                               const float* __restrict__ b1,
                                               float* __restrict__ ws) {
    __shared__ __align__(16) float lrow[3 * K_];   // 1560 floats
    __shared__ float lred[256];
    float* m1    = ws + OFF_M1;
    float* part1 = ws + OFF_PART1;
    const int t = threadIdx.x;
    const int c = t & 63, wv = t >> 6;
    const float wc0 = w1[c*6+0], wc1 = w1[c*6+1], wc2 = w1[c*6+2];
    const float wd0 = w1[c*6+3] - wc0, wd1 = w1[c*6+4] - wc1, wd2 = w1[c*6+5] - wc2;
    const float bb = b1[c];
    const int k0  = wv * 132;
    const int nIt = (wv < 3) ? 33 : 31;            // float4 groups (132/132/132/124 = 520)
    float ssum = 0.f, ssq = 0.f;
    for (int row = blockIdx.x; row < NROWS; row += gridDim.x) {
        const int b = row >> 10, n = row & 1023;
        __syncthreads();                            // protect lrow reuse
        {   // stage 3x520 floats, 390 float4 loads (rows are 16B-aligned: 520*4=2080)
            const size_t base = ((size_t)(b * 3) * N_ + n) * K_;
            for (int idx = t; idx < 390; idx += 256) {
                int ch = idx / 130;
                int k4 = idx - ch * 130;
                float4 v = *(const float4*)(ips + base + (size_t)ch * (N_ * K_) + k4 * 4);
                *(float4*)(lrow + ch * K_ + k4 * 4) = v;
            }
        }
        const float x0 = x[(b*3+0)*N_ + n], x1 = x[(b*3+1)*N_ + n], x2 = x[(b*3+2)*N_ + n];
        const float base1 = fmaf(wd0, x0, fmaf(wd1, x1, fmaf(wd2, x2, bb)));
        __syncthreads();
        float vmax = -INFINITY;
        const float* p0 = lrow + k0;
        const float* p1 = lrow + K_ + k0;
        const float* p2 = lrow + 2 * K_ + k0;
        for (int it = 0; it < nIt; ++it) {
            float4 a  = *(const float4*)(p0 + it * 4);   // broadcast LDS reads
            float4 bq = *(const float4*)(p1 + it * 4);
            float4 cq = *(const float4*)(p2 + it * 4);
            #pragma unroll
            for (int j = 0; j < 4; ++j) {
                float i0 = ((const float*)&a)[j];
                float i1 = ((const float*)&bq)[j];
                float i2 = ((const float*)&cq)[j];
                float h = fmaf(wc0, i0, fmaf(wc1, i1, fmaf(wc2, i2, base1)));
                vmax = fmaxf(vmax, h);
                ssum += h;
                ssq = fmaf(h, h, ssq);
            }
        }
        lred[t] = vmax;
        __syncthreads();
        if (t < 64) {
            float m = fmaxf(fmaxf(lred[t], lred[64 + t]), fmaxf(lred[128 + t], lred[192 + t]));
            m1[(size_t)row * 64 + t] = m;           // [row][c], coalesced
        }
    }
    // deterministic per-block stat partials
    __syncthreads();
    lred[t] = ssum;
    __syncthreads();
    if (t < 64) part1[blockIdx.x * 128 + t] = lred[t] + lred[64+t] + lred[128+t] + lred[192+t];
    __syncthreads();
    lred[t] = ssq;
    __syncthreads();
    if (t < 64) part1[blockIdx.x * 128 + 64 + t] = lred[t] + lred[64+t] + lred[128+t] + lred[192+t];
}

// ---------------- K2: reduce part1 (512x128) -> sums1[128] ----------------------
__global__ __launch_bounds__(256) void k2_red1(float* __restrict__ ws) {
    __shared__ float lds[256];
    const int t = threadIdx.x;
    const float* part1 = ws + OFF_PART1;
    const int j = t & 127, h = t >> 7;
    float s = 0.f;
    for (int p = h; p < 512; p += 2) s += part1[p * 128 + j];
    lds[t] = s;
    __syncthreads();
    if (t < 128) ws[OFF_SUMS1 + t] = lds[t] + lds[128 + t];
}

// ---------------- K3: r1 = relu(BN1(m1)); h2 = w2 @ r1 + b2; BN2 stat partials --
// Grid 256 blocks x 16 columns. Block: 256 threads = 2 col-groups x 128 out-ch.
__global__ __launch_bounds__(256) void k3_l2(const float* __restrict__ w2,
                                             const float* __restrict__ b2,
                                             const float* __restrict__ g1,
                                             const float* __restrict__ be1,
                                             float* __restrict__ ws) {
    __shared__ float w2l[C2 * 65];   // pad 65: dot-loop banks (o+i)%32 -> 2-way, free
    __shared__ float sc1[64], sh1[64];
    __shared__ float r1c[128];
    __shared__ float lred[256];
    const int t = threadIdx.x;
    const float* sums1 = ws + OFF_SUMS1;
    const float* m1    = ws + OFF_M1;
    float* h2    = ws + OFF_H2;
    float* part2 = ws + OFF_PART2;
    if (t < 64) {
        float mean = sums1[t] * (1.f / CNT1);
        float var  = sums1[64 + t] * (1.f / CNT1) - mean * mean;
        float rs   = rsqrtf(var + EPS_);
        float sc   = g1[t] * rs;
        sc1[t] = sc;
        sh1[t] = fmaf(-mean, sc, be1[t]);
    }
    for (int idx = t; idx < C2 * 64; idx += 256) {  // stage w2, padded rows
        int o = idx >> 6, i = idx & 63;
        w2l[o * 65 + i] = w2[idx];
    }
    const int o = t & 127, cg = t >> 7;
    const float bo = b2[o];
    float s2 = 0.f, q2 = 0.f;
    const int colbase = blockIdx.x * 16;
    __syncthreads();
    for (int it = 0; it < 8; ++it) {
        __syncthreads();                            // protect r1c reuse
        if (t < 128) {
            int ci = t & 63, g = t >> 6;
            float v = m1[(size_t)(colbase + it * 2 + g) * 64 + ci];
            r1c[t] = fmaxf(0.f, fmaf(v, sc1[ci], sh1[ci]));
        }
        __syncthreads();
        float acc = 0.f;
        const float* wr = w2l + o * 65;
        const float* rr = r1c + cg * 64;
        #pragma unroll 8
        for (int i = 0; i < 64; ++i) acc = fmaf(wr[i], rr[i], acc);
        float h = acc + bo;
        h2[(size_t)(colbase + it * 2 + cg) * 128 + o] = h;   // [col][o], coalesced
        s2 += h;
        q2 = fmaf(h, h, q2);
    }
    __syncthreads();
    lred[t] = s2;
    __syncthreads();
    if (t < 128) part2[blockIdx.x * 256 + t] = lred[t] + lred[128 + t];
    __syncthreads();
    lred[t] = q2;
    __syncthreads();
    if (t < 128) part2[blockIdx.x * 256 + 128 + t] = lred[t] + lred[128 + t];
}

// ---------------- K4: reduce part2 (256x256) -> sums2[256] ----------------------
__global__ __launch_bounds__(256) void k4_red2(float* __restrict__ ws) {
    const int t = threadIdx.x;
    const float* part2 = ws + OFF_PART2;
    float s = 0.f;
    for (int p = 0; p < 256; ++p) s += part2[p * 256 + t];  // coalesced
    ws[OFF_SUMS2 + t] = s;
}

// ---------------- K5: r2 = relu(BN2(h2)); h3 = w3 @ r2 + b3; tile partials ------
// Grid 512 blocks; tile = 8 consecutive n of one b, all 1024 out channels.
// Thread t owns channels 4t..4t+3 (float4 w3t loads), 8 cols -> 32 accumulators.
__global__ __launch_bounds__(256) void k5_l3(const float* __restrict__ b3,
                                             const float* __restrict__ g2,
                                             const float* __restrict__ be2,
                                             float* __restrict__ ws) {
    __shared__ __align__(16) float r2t[128 * 8];
    __shared__ float sc2[128], sh2[128];
    const int t = threadIdx.x;
    const float* sums2 = ws + OFF_SUMS2;
    const float* h2    = ws + OFF_H2;
    const float* w3t   = ws + OFF_W3T;
    float* psum = ws + OFF_PSUM;
    float* psq  = ws + OFF_PSQ;
    float* pmax = ws + OFF_PMAX;
    const int tile = blockIdx.x;                    // 0..511
    const int b = tile >> 7, n0 = (tile & 127) * 8;
    if (t < 128) {
        float mean = sums2[t] * (1.f / CNT2);
        float var  = sums2[128 + t] * (1.f / CNT2) - mean * mean;
        float rs   = rsqrtf(var + EPS_);
        float sc   = g2[t] * rs;
        sc2[t] = sc;
        sh2[t] = fmaf(-mean, sc, be2[t]);
    }
    __syncthreads();
    #pragma unroll
    for (int m = 0; m < 4; ++m) {                   // stage r2 tile [i][col]
        int idx = t + 256 * m;
        int col = idx >> 7, i = idx & 127;
        float v = h2[(size_t)(b * N_ + n0 + col) * 128 + i];
        r2t[i * 8 + col] = fmaxf(0.f, fmaf(v, sc2[i], sh2[i]));
    }
    __syncthreads();
    float acc[4][8];
    #pragma unroll
    for (int a = 0; a < 4; ++a)
        #pragma unroll
        for (int cl = 0; cl < 8; ++cl) acc[a][cl] = 0.f;
    const float4* w3t4 = (const float4*)w3t;
    for (int i = 0; i < 128; ++i) {
        float4 w  = w3t4[i * 256 + t];              // coalesced, L2-resident
        float4 ra = *(const float4*)(r2t + i * 8);  // broadcast
        float4 rb = *(const float4*)(r2t + i * 8 + 4);
        float wa[4] = {w.x, w.y, w.z, w.w};
        float rc[8] = {ra.x, ra.y, ra.z, ra.w, rb.x, rb.y, rb.z, rb.w};
        #pragma unroll
        for (int a = 0; a < 4; ++a)
            #pragma unroll
            for (int cl = 0; cl < 8; ++cl)
                acc[a][cl] = fmaf(wa[a], rc[cl], acc[a][cl]);
    }
    float4 b3v = ((const float4*)b3)[t];
    float bav[4] = {b3v.x, b3v.y, b3v.z, b3v.w};
    float4 vs, vq, vm;
    float* pvs = (float*)&vs; float* pvq = (float*)&vq; float* pvm = (float*)&vm;
    #pragma unroll
    for (int a = 0; a < 4; ++a) {
        float s = 0.f, q = 0.f, mx = -INFINITY;
        #pragma unroll
        for (int cl = 0; cl < 8; ++cl) {
            float v = acc[a][cl] + bav[a];          // h3 incl. bias
            s += v;
            q = fmaf(v, v, q);
            mx = fmaxf(mx, v);
        }
        pvs[a] = s; pvq[a] = q; pvm[a] = mx;
    }
    ((float4*)psum)[tile * 256 + t] = vs;           // [tile][c] float4, coalesced
    ((float4*)psq )[tile * 256 + t] = vq;
    ((float4*)pmax)[tile * 256 + t] = vm;
}

// ---------------- K6: reduce tiles -> BN3 stats; max over n; output -------------
// One block per out-channel c. Wave w reduces the max for batch b = w.
__global__ __launch_bounds__(256) void k6_out(const float* __restrict__ g3,
                                              const float* __restrict__ be3,
                                              float* __restrict__ out,
                                              const float* __restrict__ ws) {
    __shared__ float lsum[256], lsq[256];
    __shared__ float lmax[512];
    const int t = threadIdx.x;
    const int c = blockIdx.x;
    const float* psum = ws + OFF_PSUM;
    const float* psq  = ws + OFF_PSQ;
    const float* pmax = ws + OFF_PMAX;
    float s1 = psum[(size_t)t * 1024 + c] + psum[(size_t)(t + 256) * 1024 + c];
    float s2 = psq [(size_t)t * 1024 + c] + psq [(size_t)(t + 256) * 1024 + c];
    lmax[t]       = pmax[(size_t)t * 1024 + c];
    lmax[t + 256] = pmax[(size_t)(t + 256) * 1024 + c];
    lsum[t] = s1; lsq[t] = s2;
    __syncthreads();
    for (int s = 128; s > 0; s >>= 1) {
        if (t < s) { lsum[t] += lsum[t + s]; lsq[t] += lsq[t + s]; }
        __syncthreads();
    }
    float mean = lsum[0] * (1.f / CNT2);
    float var  = lsq[0] * (1.f / CNT2) - mean * mean;
    float rs   = rsqrtf(var + EPS_);
    float sc   = g3[c] * rs;
    float sh   = fmaf(-mean, sc, be3[c]);
    // max over the 128 tiles of batch b = wave index
    const int wv = t >> 6, l = t & 63;
    float v = fmaxf(lmax[wv * 128 + l], lmax[wv * 128 + 64 + l]);
    #pragma unroll
    for (int off = 32; off > 0; off >>= 1) v = fmaxf(v, __shfl_xor(v, off));
    if (l == 0) out[wv * 1024 + c] = fmaf(v, sc, sh);
}

extern "C" void kernel_launch(void* const* d_in, const int* in_sizes, int n_in,
                              void* d_out, int out_size, void* d_ws, size_t ws_size,
                              hipStream_t stream) {
    const float* x   = (const float*)d_in[0];
    const float* ips = (const float*)d_in[1];
    const float* w1  = (const float*)d_in[2];
    const float* b1  = (const float*)d_in[3];
    const float* g1  = (const float*)d_in[4];
    const float* be1 = (const float*)d_in[5];
    const float* w2  = (const float*)d_in[6];
    const float* b2  = (const float*)d_in[7];
    const float* g2  = (const float*)d_in[8];
    const float* be2 = (const float*)d_in[9];
    const float* w3  = (const float*)d_in[10];
    const float* b3  = (const float*)d_in[11];
    const float* g3  = (const float*)d_in[12];
    const float* be3 = (const float*)d_in[13];
    float* out = (float*)d_out;
    float* ws  = (float*)d_ws;

    hipLaunchKernelGGL(k0_w3t,  dim3(512),  dim3(256), 0, stream, w3, ws);
    hipLaunchKernelGGL(k1_feat, dim3(512),  dim3(256), 0, stream, x, ips, w1, b1, ws);
    hipLaunchKernelGGL(k2_red1, dim3(1),    dim3(256), 0, stream, ws);
    hipLaunchKernelGGL(k3_l2,   dim3(256),  dim3(256), 0, stream, w2, b2, g1, be1, ws);
    hipLaunchKernelGGL(k4_red2, dim3(1),    dim3(256), 0, stream, ws);
    hipLaunchKernelGGL(k5_l3,   dim3(512),  dim3(256), 0, stream, b3, g2, be2, ws);
    hipLaunchKernelGGL(k6_out,  dim3(1024), dim3(256), 0, stream, g3, be3, out, ws);
}

// Round 2
// 89.083 us; speedup vs baseline: 1.7516x; 1.7516x over previous
//
#include <hip/hip_runtime.h>
#include <math.h>

// Problem constants
#define B_   4
#define N_   1024
#define K_   520
#define C1   64
#define C2   128
#define C3   1024
#define NROWS (B_*N_)                 // 4096
#define CNT1  ((float)(B_*N_*K_))     // 2129920
#define CNT2  ((float)(B_*N_))        // 4096
#define EPS_  1e-5f

// Workspace layout (float offsets). Total = 2,621,824 floats ~= 10.5 MB.
#define OFF_SUMS1   0                         // 128  (64 sum, 64 sumsq)
#define OFF_SUMS2   128                       // 256  (128 sum, 128 sumsq)
#define OFF_PART1   384                       // 512*128
#define OFF_PART2   (OFF_PART1 + 512*128)     // 256*256
#define OFF_M1      (OFF_PART2 + 256*256)     // 4096*64   max_k h1, layout [row][c]
#define OFF_H2      (OFF_M1 + 4096*64)        // 4096*128  layout [col][o]
#define OFF_W3T     (OFF_H2 + 4096*128)       // 128*1024  w3 transposed [i][o]
#define OFF_PSUM    (OFF_W3T + 128*1024)      // 512*1024  per-tile channel sums of h3
#define OFF_PSQ     (OFF_PSUM + 512*1024)     // 512*1024
#define OFF_PMAX    (OFF_PSQ + 512*1024)      // 512*1024

// ---------------- K0: transpose w3 (1024x128) -> w3t (128x1024) ----------------
__global__ __launch_bounds__(256) void k0_w3t(const float* __restrict__ w3,
                                              float* __restrict__ ws) {
    float* w3t = ws + OFF_W3T;
    int idx = blockIdx.x * 256 + threadIdx.x;      // 0..131071
    int i = idx >> 10, o = idx & 1023;
    w3t[idx] = w3[o * 128 + i];                    // coalesced writes
}

// ---------------- K1: fused conv1 (6->64) + BN1 stats + max over K --------------
// Each block grid-strides over rows (b,n). 4 waves: wave wv handles k-chunk
// [wv*132, +132) (last: 124). Thread t: channel c = t&63.
// h = w[c][0..2]*ips + base, base folds the (x) half of feat and bias.
__global__ __launch_bounds__(256) void k1_feat(const float* __restrict__ x,
                                               const float* __restrict__ ips,
                                               const float* __restrict__ w1,
                                               const float* __restrict__ b1,
                                               float* __restrict__ ws) {
    __shared__ __align__(16) float lrow[3 * K_];   // 1560 floats
    __shared__ float lred[256];
    float* m1    = ws + OFF_M1;
    float* part1 = ws + OFF_PART1;
    const int t = threadIdx.x;
    const int c = t & 63, wv = t >> 6;
    const float wc0 = w1[c*6+0], wc1 = w1[c*6+1], wc2 = w1[c*6+2];
    const float wd0 = w1[c*6+3] - wc0, wd1 = w1[c*6+4] - wc1, wd2 = w1[c*6+5] - wc2;
    const float bb = b1[c];
    const int k0  = wv * 132;
    const int nIt = (wv < 3) ? 33 : 31;            // float4 groups (132/132/132/124 = 520)
    float ssum = 0.f, ssq = 0.f;
    for (int row = blockIdx.x; row < NROWS; row += gridDim.x) {
        const int b = row >> 10, n = row & 1023;
        __syncthreads();                            // protect lrow reuse
        {   // stage 3x520 floats, 390 float4 loads (rows are 16B-aligned: 520*4=2080)
            const size_t base = ((size_t)(b * 3) * N_ + n) * K_;
            for (int idx = t; idx < 390; idx += 256) {
                int ch = idx / 130;
                int k4 = idx - ch * 130;
                float4 v = *(const float4*)(ips + base + (size_t)ch * (N_ * K_) + k4 * 4);
                *(float4*)(lrow + ch * K_ + k4 * 4) = v;
            }
        }
        const float x0 = x[(b*3+0)*N_ + n], x1 = x[(b*3+1)*N_ + n], x2 = x[(b*3+2)*N_ + n];
        const float base1 = fmaf(wd0, x0, fmaf(wd1, x1, fmaf(wd2, x2, bb)));
        __syncthreads();
        float vmax = -INFINITY;
        const float* p0 = lrow + k0;
        const float* p1 = lrow + K_ + k0;
        const float* p2 = lrow + 2 * K_ + k0;
        for (int it = 0; it < nIt; ++it) {
            float4 a  = *(const float4*)(p0 + it * 4);   // broadcast LDS reads
            float4 bq = *(const float4*)(p1 + it * 4);
            float4 cq = *(const float4*)(p2 + it * 4);
            #pragma unroll
            for (int j = 0; j < 4; ++j) {
                float i0 = ((const float*)&a)[j];
                float i1 = ((const float*)&bq)[j];
                float i2 = ((const float*)&cq)[j];
                float h = fmaf(wc0, i0, fmaf(wc1, i1, fmaf(wc2, i2, base1)));
                vmax = fmaxf(vmax, h);
                ssum += h;
                ssq = fmaf(h, h, ssq);
            }
        }
        lred[t] = vmax;
        __syncthreads();
        if (t < 64) {
            float m = fmaxf(fmaxf(lred[t], lred[64 + t]), fmaxf(lred[128 + t], lred[192 + t]));
            m1[(size_t)row * 64 + t] = m;           // [row][c], coalesced
        }
    }
    // deterministic per-block stat partials
    __syncthreads();
    lred[t] = ssum;
    __syncthreads();
    if (t < 64) part1[blockIdx.x * 128 + t] = lred[t] + lred[64+t] + lred[128+t] + lred[192+t];
    __syncthreads();
    lred[t] = ssq;
    __syncthreads();
    if (t < 64) part1[blockIdx.x * 128 + 64 + t] = lred[t] + lred[64+t] + lred[128+t] + lred[192+t];
}

// ---------------- K2: reduce part1 (512x128) -> sums1[128] ----------------------
// One block per stat channel j; 512 partials loaded in parallel, LDS tree.
__global__ __launch_bounds__(256) void k2_red1(float* __restrict__ ws) {
    __shared__ float lds[256];
    const int t = threadIdx.x;
    const int j = blockIdx.x;                       // 0..127
    const float* part1 = ws + OFF_PART1;
    lds[t] = part1[t * 128 + j] + part1[(t + 256) * 128 + j];
    __syncthreads();
    for (int st = 128; st > 0; st >>= 1) {
        if (t < st) lds[t] += lds[t + st];
        __syncthreads();
    }
    if (t == 0) ws[OFF_SUMS1 + j] = lds[0];
}

// ---------------- K3: r1 = relu(BN1(m1)); h2 = w2 @ r1 + b2; BN2 stat partials --
// Grid 256 blocks x 16 columns. Block: 256 threads = 2 col-groups x 128 out-ch.
__global__ __launch_bounds__(256) void k3_l2(const float* __restrict__ w2,
                                             const float* __restrict__ b2,
                                             const float* __restrict__ g1,
                                             const float* __restrict__ be1,
                                             float* __restrict__ ws) {
    __shared__ float w2l[C2 * 65];   // pad 65: dot-loop banks (o+i)%32 -> 2-way, free
    __shared__ float sc1[64], sh1[64];
    __shared__ float r1c[128];
    __shared__ float lred[256];
    const int t = threadIdx.x;
    const float* sums1 = ws + OFF_SUMS1;
    const float* m1    = ws + OFF_M1;
    float* h2    = ws + OFF_H2;
    float* part2 = ws + OFF_PART2;
    if (t < 64) {
        float mean = sums1[t] * (1.f / CNT1);
        float var  = sums1[64 + t] * (1.f / CNT1) - mean * mean;
        float rs   = rsqrtf(var + EPS_);
        float sc   = g1[t] * rs;
        sc1[t] = sc;
        sh1[t] = fmaf(-mean, sc, be1[t]);
    }
    for (int idx = t; idx < C2 * 64; idx += 256) {  // stage w2, padded rows
        int o = idx >> 6, i = idx & 63;
        w2l[o * 65 + i] = w2[idx];
    }
    const int o = t & 127, cg = t >> 7;
    const float bo = b2[o];
    float s2 = 0.f, q2 = 0.f;
    const int colbase = blockIdx.x * 16;
    __syncthreads();
    for (int it = 0; it < 8; ++it) {
        __syncthreads();                            // protect r1c reuse
        if (t < 128) {
            int ci = t & 63, g = t >> 6;
            float v = m1[(size_t)(colbase + it * 2 + g) * 64 + ci];
            r1c[t] = fmaxf(0.f, fmaf(v, sc1[ci], sh1[ci]));
        }
        __syncthreads();
        float acc = 0.f;
        const float* wr = w2l + o * 65;
        const float* rr = r1c + cg * 64;
        #pragma unroll 8
        for (int i = 0; i < 64; ++i) acc = fmaf(wr[i], rr[i], acc);
        float h = acc + bo;
        h2[(size_t)(colbase + it * 2 + cg) * 128 + o] = h;   // [col][o], coalesced
        s2 += h;
        q2 = fmaf(h, h, q2);
    }
    __syncthreads();
    lred[t] = s2;
    __syncthreads();
    if (t < 128) part2[blockIdx.x * 256 + t] = lred[t] + lred[128 + t];
    __syncthreads();
    lred[t] = q2;
    __syncthreads();
    if (t < 128) part2[blockIdx.x * 256 + 128 + t] = lred[t] + lred[128 + t];
}

// ---------------- K4: reduce part2 (256x256) -> sums2[256] ----------------------
// One block per stat channel c; 256 partials loaded in parallel, LDS tree.
__global__ __launch_bounds__(256) void k4_red2(float* __restrict__ ws) {
    __shared__ float lds[256];
    const int t = threadIdx.x;
    const int c = blockIdx.x;                       // 0..255
    const float* part2 = ws + OFF_PART2;
    lds[t] = part2[t * 256 + c];
    __syncthreads();
    for (int st = 128; st > 0; st >>= 1) {
        if (t < st) lds[t] += lds[t + st];
        __syncthreads();
    }
    if (t == 0) ws[OFF_SUMS2 + c] = lds[0];
}

// ---------------- K5: r2 = relu(BN2(h2)); h3 = w3 @ r2 + b3; tile partials ------
// Grid 512 blocks; tile = 8 consecutive n of one b, all 1024 out channels.
// Thread t owns channels 4t..4t+3 (float4 w3t loads), 8 cols -> 32 accumulators.
__global__ __launch_bounds__(256) void k5_l3(const float* __restrict__ b3,
                                             const float* __restrict__ g2,
                                             const float* __restrict__ be2,
                                             float* __restrict__ ws) {
    __shared__ __align__(16) float r2t[128 * 8];
    __shared__ float sc2[128], sh2[128];
    const int t = threadIdx.x;
    const float* sums2 = ws + OFF_SUMS2;
    const float* h2    = ws + OFF_H2;
    const float* w3t   = ws + OFF_W3T;
    float* psum = ws + OFF_PSUM;
    float* psq  = ws + OFF_PSQ;
    float* pmax = ws + OFF_PMAX;
    const int tile = blockIdx.x;                    // 0..511
    const int b = tile >> 7, n0 = (tile & 127) * 8;
    if (t < 128) {
        float mean = sums2[t] * (1.f / CNT2);
        float var  = sums2[128 + t] * (1.f / CNT2) - mean * mean;
        float rs   = rsqrtf(var + EPS_);
        float sc   = g2[t] * rs;
        sc2[t] = sc;
        sh2[t] = fmaf(-mean, sc, be2[t]);
    }
    __syncthreads();
    #pragma unroll
    for (int m = 0; m < 4; ++m) {                   // stage r2 tile [i][col]
        int idx = t + 256 * m;
        int col = idx >> 7, i = idx & 127;
        float v = h2[(size_t)(b * N_ + n0 + col) * 128 + i];
        r2t[i * 8 + col] = fmaxf(0.f, fmaf(v, sc2[i], sh2[i]));
    }
    __syncthreads();
    float acc[4][8];
    #pragma unroll
    for (int a = 0; a < 4; ++a)
        #pragma unroll
        for (int cl = 0; cl < 8; ++cl) acc[a][cl] = 0.f;
    const float4* w3t4 = (const float4*)w3t;
    for (int i = 0; i < 128; ++i) {
        float4 w  = w3t4[i * 256 + t];              // coalesced, L2-resident
        float4 ra = *(const float4*)(r2t + i * 8);  // broadcast
        float4 rb = *(const float4*)(r2t + i * 8 + 4);
        float wa[4] = {w.x, w.y, w.z, w.w};
        float rc[8] = {ra.x, ra.y, ra.z, ra.w, rb.x, rb.y, rb.z, rb.w};
        #pragma unroll
        for (int a = 0; a < 4; ++a)
            #pragma unroll
            for (int cl = 0; cl < 8; ++cl)
                acc[a][cl] = fmaf(wa[a], rc[cl], acc[a][cl]);
    }
    float4 b3v = ((const float4*)b3)[t];
    float bav[4] = {b3v.x, b3v.y, b3v.z, b3v.w};
    float4 vs, vq, vm;
    float* pvs = (float*)&vs; float* pvq = (float*)&vq; float* pvm = (float*)&vm;
    #pragma unroll
    for (int a = 0; a < 4; ++a) {
        float s = 0.f, q = 0.f, mx = -INFINITY;
        #pragma unroll
        for (int cl = 0; cl < 8; ++cl) {
            float v = acc[a][cl] + bav[a];          // h3 incl. bias
            s += v;
            q = fmaf(v, v, q);
            mx = fmaxf(mx, v);
        }
        pvs[a] = s; pvq[a] = q; pvm[a] = mx;
    }
    ((float4*)psum)[tile * 256 + t] = vs;           // [tile][c] float4, coalesced
    ((float4*)psq )[tile * 256 + t] = vq;
    ((float4*)pmax)[tile * 256 + t] = vm;
}

// ---------------- K6: reduce tiles -> BN3 stats; max over n; output -------------
// One block per out-channel c. Wave w reduces the max for batch b = w.
__global__ __launch_bounds__(256) void k6_out(const float* __restrict__ g3,
                                              const float* __restrict__ be3,
                                              float* __restrict__ out,
                                              const float* __restrict__ ws) {
    __shared__ float lsum[256], lsq[256];
    __shared__ float lmax[512];
    const int t = threadIdx.x;
    const int c = blockIdx.x;
    const float* psum = ws + OFF_PSUM;
    const float* psq  = ws + OFF_PSQ;
    const float* pmax = ws + OFF_PMAX;
    float s1 = psum[(size_t)t * 1024 + c] + psum[(size_t)(t + 256) * 1024 + c];
    float s2 = psq [(size_t)t * 1024 + c] + psq [(size_t)(t + 256) * 1024 + c];
    lmax[t]       = pmax[(size_t)t * 1024 + c];
    lmax[t + 256] = pmax[(size_t)(t + 256) * 1024 + c];
    lsum[t] = s1; lsq[t] = s2;
    __syncthreads();
    for (int s = 128; s > 0; s >>= 1) {
        if (t < s) { lsum[t] += lsum[t + s]; lsq[t] += lsq[t + s]; }
        __syncthreads();
    }
    float mean = lsum[0] * (1.f / CNT2);
    float var  = lsq[0] * (1.f / CNT2) - mean * mean;
    float rs   = rsqrtf(var + EPS_);
    float sc   = g3[c] * rs;
    float sh   = fmaf(-mean, sc, be3[c]);
    // max over the 128 tiles of batch b = wave index
    const int wv = t >> 6, l = t & 63;
    float v = fmaxf(lmax[wv * 128 + l], lmax[wv * 128 + 64 + l]);
    #pragma unroll
    for (int off = 32; off > 0; off >>= 1) v = fmaxf(v, __shfl_xor(v, off));
    if (l == 0) out[wv * 1024 + c] = fmaf(v, sc, sh);
}

extern "C" void kernel_launch(void* const* d_in, const int* in_sizes, int n_in,
                              void* d_out, int out_size, void* d_ws, size_t ws_size,
                              hipStream_t stream) {
    const float* x   = (const float*)d_in[0];
    const float* ips = (const float*)d_in[1];
    const float* w1  = (const float*)d_in[2];
    const float* b1  = (const float*)d_in[3];
    const float* g1  = (const float*)d_in[4];
    const float* be1 = (const float*)d_in[5];
    const float* w2  = (const float*)d_in[6];
    const float* b2  = (const float*)d_in[7];
    const float* g2  = (const float*)d_in[8];
    const float* be2 = (const float*)d_in[9];
    const float* w3  = (const float*)d_in[10];
    const float* b3  = (const float*)d_in[11];
    const float* g3  = (const float*)d_in[12];
    const float* be3 = (const float*)d_in[13];
    float* out = (float*)d_out;
    float* ws  = (float*)d_ws;

    hipLaunchKernelGGL(k0_w3t,  dim3(512),  dim3(256), 0, stream, w3, ws);
    hipLaunchKernelGGL(k1_feat, dim3(512),  dim3(256), 0, stream, x, ips, w1, b1, ws);
    hipLaunchKernelGGL(k2_red1, dim3(128),  dim3(256), 0, stream, ws);
    hipLaunchKernelGGL(k3_l2,   dim3(256),  dim3(256), 0, stream, w2, b2, g1, be1, ws);
    hipLaunchKernelGGL(k4_red2, dim3(256),  dim3(256), 0, stream, ws);
    hipLaunchKernelGGL(k5_l3,   dim3(512),  dim3(256), 0, stream, b3, g2, be2, ws);
    hipLaunchKernelGGL(k6_out,  dim3(1024), dim3(256), 0, stream, g3, be3, out, ws);
}

// Round 3
// 78.881 us; speedup vs baseline: 1.9781x; 1.1293x over previous
//
#include <hip/hip_runtime.h>
#include <math.h>

// Problem constants
#define B_   4
#define N_   1024
#define K_   520
#define C2   128
#define NROWS (B_*N_)                 // 4096
#define CNT1  ((float)(B_*N_*K_))     // 2129920
#define CNT2  ((float)(B_*N_))        // 4096
#define EPS_  1e-5f

// Workspace layout (float offsets). Total 1,868,160 floats ~= 7.5 MB.
#define OFF_SC1     0                          // sc1[64], sh1[64]
#define OFF_SC2     128                        // sc2[128], sh2[128]
#define OFF_PART1   384                        // 1024 x 32 moment partials
#define OFF_PART2   (OFF_PART1 + 1024*32)      // 512 x 256
#define OFF_M1      (OFF_PART2 + 512*256)      // 4096*64   max_k h1, [row][c]
#define OFF_H2      (OFF_M1 + 4096*64)         // 4096*128  [col][o]
#define OFF_W3T     (OFF_H2 + 4096*128)        // 128*1024  w3^T [i][o]
#define OFF_PSUM    (OFF_W3T + 128*1024)       // 256*1024  per-tile sums of h3
#define OFF_PSQ     (OFF_PSUM + 256*1024)      // 256*1024
#define OFF_PMAX    (OFF_PSQ + 256*1024)       // 256*1024

// ---------------- K1: conv1 max over K + 27 global moment partials ----------------
// 1024 blocks x 4 rows. 4 waves split K (132/132/132/124). Lane = channel for the
// max pass; lanes 0..nIt-1 = k-groups for the moment pass.
// Moment slots per block (part1[bid][32]):
//  0-5:  Mg = sum_{r,k} [i0i0,i0i1,i0i2,i1i1,i1i2,i2i2]
//  6-8:  Sg = sum_{r,k} [i0,i1,i2]
//  9-17: P[i][j] = sum_r S_i(r)*x_j(r)   (row-major)
// 18-23: Q = sum_r [x0x0,x0x1,x0x2,x1x1,x1x2,x2x2]
// 24-26: X = sum_r [x0,x1,x2]
__global__ __launch_bounds__(256) void k1_feat(const float* __restrict__ x,
                                               const float* __restrict__ ips,
                                               const float* __restrict__ w1,
                                               const float* __restrict__ b1,
                                               float* __restrict__ ws) {
    __shared__ __align__(16) float lrow[3 * K_];   // 1560 floats
    __shared__ float lred[256];
    __shared__ float sred[12];                     // per-wave S partials [wv*3+comp]
    __shared__ float mredl[24];                    // per-wave Mg partials [wv*6+j]
    float* m1    = ws + OFF_M1;
    float* part1 = ws + OFF_PART1;
    const int t = threadIdx.x;
    const int c = t & 63, wv = t >> 6, lane = t & 63;
    const float wc0 = w1[c*6+0], wc1 = w1[c*6+1], wc2 = w1[c*6+2];
    const float wd0 = w1[c*6+3] - wc0, wd1 = w1[c*6+4] - wc1, wd2 = w1[c*6+5] - wc2;
    const float bb = b1[c];
    const int k0  = wv * 132;
    const int nIt = (wv < 3) ? 33 : 31;            // float4 groups per wave chunk
    float mm[6] = {0.f,0.f,0.f,0.f,0.f,0.f};       // per-lane Mg partials
    float pqx = 0.f;                               // block-level P/Q/X/Sg (t<21)
    for (int row = blockIdx.x; row < NROWS; row += 1024) {
        const int b = row >> 10, n = row & 1023;
        __syncthreads();                            // protect lrow/sred/lred reuse
        {   // stage 3x520 floats (rows 16B-aligned: 520*4=2080)
            const size_t base = ((size_t)(b * 3) * N_ + n) * K_;
            for (int idx = t; idx < 390; idx += 256) {
                int ch = idx / 130;
                int k4 = idx - ch * 130;
                float4 v = *(const float4*)(ips + base + (size_t)ch * (N_ * K_) + k4 * 4);
                *(float4*)(lrow + ch * K_ + k4 * 4) = v;
            }
        }
        const float x0 = x[(b*3+0)*N_ + n], x1 = x[(b*3+1)*N_ + n], x2 = x[(b*3+2)*N_ + n];
        const float base1 = fmaf(wd0, x0, fmaf(wd1, x1, fmaf(wd2, x2, bb)));
        __syncthreads();
        // ---- pass A: per-channel max over this wave's k-chunk ----
        float vmax = -INFINITY;
        const float* p0 = lrow + k0;
        const float* p1 = lrow + K_ + k0;
        const float* p2 = lrow + 2 * K_ + k0;
        for (int it = 0; it < nIt; ++it) {
            float4 a  = *(const float4*)(p0 + it * 4);   // broadcast LDS reads
            float4 bq = *(const float4*)(p1 + it * 4);
            float4 cq = *(const float4*)(p2 + it * 4);
            #pragma unroll
            for (int j = 0; j < 4; ++j) {
                float i0 = ((const float*)&a)[j];
                float i1 = ((const float*)&bq)[j];
                float i2 = ((const float*)&cq)[j];
                float h = fmaf(wc0, i0, fmaf(wc1, i1, fmaf(wc2, i2, base1)));
                vmax = fmaxf(vmax, h);
            }
        }
        lred[t] = vmax;
        // ---- pass B: k-moments, lane-parallel over k-groups ----
        float s0 = 0.f, s1 = 0.f, s2 = 0.f;
        if (lane < nIt) {
            float4 a  = *(const float4*)(p0 + lane * 4);
            float4 bq = *(const float4*)(p1 + lane * 4);
            float4 cq = *(const float4*)(p2 + lane * 4);
            #pragma unroll
            for (int j = 0; j < 4; ++j) {
                float i0 = ((const float*)&a)[j];
                float i1 = ((const float*)&bq)[j];
                float i2 = ((const float*)&cq)[j];
                mm[0] = fmaf(i0, i0, mm[0]); mm[1] = fmaf(i0, i1, mm[1]);
                mm[2] = fmaf(i0, i2, mm[2]); mm[3] = fmaf(i1, i1, mm[3]);
                mm[4] = fmaf(i1, i2, mm[4]); mm[5] = fmaf(i2, i2, mm[5]);
                s0 += i0; s1 += i1; s2 += i2;
            }
        }
        #pragma unroll
        for (int off = 32; off > 0; off >>= 1) {
            s0 += __shfl_xor(s0, off); s1 += __shfl_xor(s1, off); s2 += __shfl_xor(s2, off);
        }
        if (lane == 0) { sred[wv*3+0] = s0; sred[wv*3+1] = s1; sred[wv*3+2] = s2; }
        __syncthreads();
        if (t < 64) {
            float m = fmaxf(fmaxf(lred[t], lred[64 + t]), fmaxf(lred[128 + t], lred[192 + t]));
            m1[(size_t)row * 64 + t] = m;           // [row][c], coalesced
        }
        if (t < 9) {            // P[i][j] += S_i(r) * x_j(r)
            int ci = t / 3, cj = t - ci * 3;
            float Sv = sred[ci] + sred[ci+3] + sred[ci+6] + sred[ci+9];
            float xj = (cj == 0) ? x0 : ((cj == 1) ? x1 : x2);
            pqx = fmaf(Sv, xj, pqx);
        } else if (t < 15) {    // Q += x x^T (upper)
            int u = t - 9;
            float xa = (u < 3) ? x0 : ((u < 5) ? x1 : x2);
            float xb = (u == 0) ? x0 : ((u == 1 || u == 3) ? x1 : x2);
            pqx = fmaf(xa, xb, pqx);
        } else if (t < 18) {    // X += x
            pqx += (t == 15) ? x0 : ((t == 16) ? x1 : x2);
        } else if (t < 21) {    // Sg += S(r)
            int comp = t - 18;
            pqx += sred[comp] + sred[comp+3] + sred[comp+6] + sred[comp+9];
        }
    }
    // ---- write block partials ----
    #pragma unroll
    for (int j = 0; j < 6; ++j) {
        float v = mm[j];
        #pragma unroll
        for (int off = 32; off > 0; off >>= 1) v += __shfl_xor(v, off);
        if (lane == 0) mredl[wv*6 + j] = v;
    }
    __syncthreads();
    if (t < 6)       part1[blockIdx.x*32 + t] = mredl[t] + mredl[6+t] + mredl[12+t] + mredl[18+t];
    if (t >= 9 && t < 18)  part1[blockIdx.x*32 + 9 + t]  = pqx;   // t<9 handled below
    if (t < 9)             part1[blockIdx.x*32 + 9 + t]  = pqx;   // P slots 9..17
    if (t >= 18 && t < 21) part1[blockIdx.x*32 + t - 12] = pqx;   // Sg slots 6..8
}

// ---------------- K2: reduce moments -> BN1 scale/shift ----------------
__global__ __launch_bounds__(512) void k2_red1(const float* __restrict__ w1,
                                               const float* __restrict__ b1,
                                               const float* __restrict__ g1,
                                               const float* __restrict__ be1,
                                               float* __restrict__ ws) {
    __shared__ float lds[512];
    __shared__ float mo[32];
    const int t = threadIdx.x;
    const float* part1 = ws + OFF_PART1;
    const int s = t & 31, g = t >> 5;               // 16 stripes
    float acc = 0.f;
    if (s < 27) {
        for (int j = 0; j < 64; ++j) acc += part1[(g*64 + j)*32 + s];
    }
    lds[t] = acc;
    __syncthreads();
    if (t < 32) {
        float m = 0.f;
        for (int gg = 0; gg < 16; ++gg) m += lds[gg*32 + t];
        mo[t] = m;
    }
    __syncthreads();
    if (t < 64) {
        const int c = t;
        float w0 = w1[c*6+0], w1v = w1[c*6+1], w2v = w1[c*6+2];
        float wd0 = w1[c*6+3]-w0, wd1 = w1[c*6+4]-w1v, wd2 = w1[c*6+5]-w2v;
        float bb = b1[c];
        float S0 = mo[6], S1 = mo[7], S2 = mo[8];
        float X0 = mo[24], X1 = mo[25], X2 = mo[26];
        float wcS = w0*S0 + w1v*S1 + w2v*S2;
        float wdX = wd0*X0 + wd1*X1 + wd2*X2;
        float ssum = wcS + 520.f*(wdX + 4096.f*bb);
        float t1 = w0*w0*mo[0] + w1v*w1v*mo[3] + w2v*w2v*mo[5]
                 + 2.f*(w0*w1v*mo[1] + w0*w2v*mo[2] + w1v*w2v*mo[4]);
        float Pt = w0 *(mo[9]*wd0  + mo[10]*wd1 + mo[11]*wd2)
                 + w1v*(mo[12]*wd0 + mo[13]*wd1 + mo[14]*wd2)
                 + w2v*(mo[15]*wd0 + mo[16]*wd1 + mo[17]*wd2);
        float t2 = 2.f*(Pt + bb*wcS);
        float Qt = wd0*wd0*mo[18] + wd1*wd1*mo[21] + wd2*wd2*mo[23]
                 + 2.f*(wd0*wd1*mo[19] + wd0*wd2*mo[20] + wd1*wd2*mo[22]);
        float t3 = 520.f*(Qt + 2.f*bb*wdX + 4096.f*bb*bb);
        float ssq = t1 + t2 + t3;
        float mean = ssum * (1.f / CNT1);
        float var  = ssq * (1.f / CNT1) - mean*mean;
        float sc   = g1[c] * rsqrtf(var + EPS_);
        ws[OFF_SC1 + c]      = sc;
        ws[OFF_SC1 + 64 + c] = fmaf(-mean, sc, be1[c]);
    }
}

// ---------------- K3: w3 transpose + r1=relu(BN1(m1)); h2 = w2@r1+b2; BN2 partials
// 512 blocks x 8 columns. 256 threads = 2 col-groups x 128 out-ch.
__global__ __launch_bounds__(256) void k3_l2(const float* __restrict__ w2,
                                             const float* __restrict__ b2,
                                             const float* __restrict__ w3,
                                             float* __restrict__ ws) {
    __shared__ float w2l[C2 * 65];
    __shared__ float sc1[64], sh1[64];
    __shared__ float r1c[128];
    __shared__ float lred[256];
    const int t = threadIdx.x;
    const float* m1 = ws + OFF_M1;
    float* h2    = ws + OFF_H2;
    float* part2 = ws + OFF_PART2;
    float* w3t   = ws + OFF_W3T;
    {   // fold w3 transpose: block covers 256 w3t elements
        int idx = blockIdx.x * 256 + t;
        int i = idx >> 10, o = idx & 1023;
        w3t[idx] = w3[o * 128 + i];
    }
    if (t < 64) { sc1[t] = ws[OFF_SC1 + t]; sh1[t] = ws[OFF_SC1 + 64 + t]; }
    for (int idx = t; idx < C2 * 64; idx += 256) {
        int o = idx >> 6, i = idx & 63;
        w2l[o * 65 + i] = w2[idx];
    }
    const int o = t & 127, cg = t >> 7;
    const float bo = b2[o];
    float s2 = 0.f, q2 = 0.f;
    const int colbase = blockIdx.x * 8;
    __syncthreads();
    for (int it = 0; it < 4; ++it) {
        __syncthreads();
        if (t < 128) {
            int ci = t & 63, g = t >> 6;
            float v = m1[(size_t)(colbase + it * 2 + g) * 64 + ci];
            r1c[t] = fmaxf(0.f, fmaf(v, sc1[ci], sh1[ci]));
        }
        __syncthreads();
        float acc = 0.f;
        const float* wr = w2l + o * 65;
        const float* rr = r1c + cg * 64;
        #pragma unroll 8
        for (int i = 0; i < 64; ++i) acc = fmaf(wr[i], rr[i], acc);
        float h = acc + bo;
        h2[(size_t)(colbase + it * 2 + cg) * 128 + o] = h;
        s2 += h;
        q2 = fmaf(h, h, q2);
    }
    __syncthreads();
    lred[t] = s2;
    __syncthreads();
    if (t < 128) part2[blockIdx.x * 256 + t] = lred[t] + lred[128 + t];
    __syncthreads();
    lred[t] = q2;
    __syncthreads();
    if (t < 128) part2[blockIdx.x * 256 + 128 + t] = lred[t] + lred[128 + t];
}

// ---------------- K4: reduce part2 (512x256) -> BN2 scale/shift ----------------
// 128 blocks, one per channel; both sum and sumsq.
__global__ __launch_bounds__(256) void k4_red2(const float* __restrict__ g2,
                                               const float* __restrict__ be2,
                                               float* __restrict__ ws) {
    __shared__ float lsum[256], lsq[256];
    const int t = threadIdx.x;
    const int c = blockIdx.x;                       // 0..127
    const float* part2 = ws + OFF_PART2;
    lsum[t] = part2[t*256 + c]       + part2[(t+256)*256 + c];
    lsq[t]  = part2[t*256 + 128 + c] + part2[(t+256)*256 + 128 + c];
    __syncthreads();
    for (int st = 128; st > 0; st >>= 1) {
        if (t < st) { lsum[t] += lsum[t + st]; lsq[t] += lsq[t + st]; }
        __syncthreads();
    }
    if (t == 0) {
        float mean = lsum[0] * (1.f / CNT2);
        float var  = lsq[0] * (1.f / CNT2) - mean*mean;
        float sc   = g2[c] * rsqrtf(var + EPS_);
        ws[OFF_SC2 + c]       = sc;
        ws[OFF_SC2 + 128 + c] = fmaf(-mean, sc, be2[c]);
    }
}

// ---------------- K5: r2 = relu(BN2(h2)); h3 = w3@r2+b3; tile partials ----------
// 256 blocks x 512 threads; tile = 16 consecutive n of one b, all 1024 channels.
// Thread t owns channels 2t..2t+1 (float2 w3t loads), 16 cols -> 32 accumulators.
__global__ __launch_bounds__(512) void k5_l3(const float* __restrict__ b3,
                                             float* __restrict__ ws) {
    __shared__ __align__(16) float r2t[128 * 16];
    __shared__ float sc2[128], sh2[128];
    const int t = threadIdx.x;
    const float* h2  = ws + OFF_H2;
    const float* w3t = ws + OFF_W3T;
    float* psum = ws + OFF_PSUM;
    float* psq  = ws + OFF_PSQ;
    float* pmax = ws + OFF_PMAX;
    const int tile = blockIdx.x;                    // 0..255
    const int b = tile >> 6, n0 = (tile & 63) * 16;
    if (t < 128) { sc2[t] = ws[OFF_SC2 + t]; sh2[t] = ws[OFF_SC2 + 128 + t]; }
    __syncthreads();
    #pragma unroll
    for (int m = 0; m < 4; ++m) {                   // stage r2 tile [i][col]
        int idx = t + 512 * m;
        int col = idx >> 7, i = idx & 127;
        float v = h2[(size_t)(b * N_ + n0 + col) * 128 + i];
        r2t[i * 16 + col] = fmaxf(0.f, fmaf(v, sc2[i], sh2[i]));
    }
    __syncthreads();
    float acc[2][16];
    #pragma unroll
    for (int a = 0; a < 2; ++a)
        #pragma unroll
        for (int cl = 0; cl < 16; ++cl) acc[a][cl] = 0.f;
    const float2* w3t2 = (const float2*)w3t;
    for (int i = 0; i < 128; ++i) {
        float2 w = w3t2[i * 512 + t];               // coalesced, L2-resident
        float wa0 = w.x, wa1 = w.y;
        const float4* rp = (const float4*)(r2t + i * 16);
        #pragma unroll
        for (int q = 0; q < 4; ++q) {
            float4 r4 = rp[q];                      // broadcast LDS read
            float rc[4] = {r4.x, r4.y, r4.z, r4.w};
            #pragma unroll
            for (int jj = 0; jj < 4; ++jj) {
                acc[0][q*4+jj] = fmaf(wa0, rc[jj], acc[0][q*4+jj]);
                acc[1][q*4+jj] = fmaf(wa1, rc[jj], acc[1][q*4+jj]);
            }
        }
    }
    float2 b3v = ((const float2*)b3)[t];
    float bav[2] = {b3v.x, b3v.y};
    float2 vs, vq, vm;
    float* pvs = (float*)&vs; float* pvq = (float*)&vq; float* pvm = (float*)&vm;
    #pragma unroll
    for (int a = 0; a < 2; ++a) {
        float s = 0.f, q = 0.f, mx = -INFINITY;
        #pragma unroll
        for (int cl = 0; cl < 16; ++cl) {
            float v = acc[a][cl] + bav[a];
            s += v;
            q = fmaf(v, v, q);
            mx = fmaxf(mx, v);
        }
        pvs[a] = s; pvq[a] = q; pvm[a] = mx;
    }
    ((float2*)psum)[tile * 512 + t] = vs;           // [tile][c], coalesced
    ((float2*)psq )[tile * 512 + t] = vq;
    ((float2*)pmax)[tile * 512 + t] = vm;
}

// ---------------- K6: BN3 stats from tiles; max over n; output ------------------
// One block per out-channel c; 256 tiles. Wave wv reduces batch wv (64 tiles).
__global__ __launch_bounds__(256) void k6_out(const float* __restrict__ g3,
                                              const float* __restrict__ be3,
                                              float* __restrict__ out,
                                              const float* __restrict__ ws) {
    __shared__ float lsum[256], lsq[256], lmax[256];
    const int t = threadIdx.x;
    const int c = blockIdx.x;
    const float* psum = ws + OFF_PSUM;
    const float* psq  = ws + OFF_PSQ;
    const float* pmax = ws + OFF_PMAX;
    lsum[t] = psum[(size_t)t * 1024 + c];
    lsq[t]  = psq [(size_t)t * 1024 + c];
    lmax[t] = pmax[(size_t)t * 1024 + c];
    __syncthreads();
    for (int s = 128; s > 0; s >>= 1) {
        if (t < s) { lsum[t] += lsum[t + s]; lsq[t] += lsq[t + s]; }
        __syncthreads();
    }
    float mean = lsum[0] * (1.f / CNT2);
    float var  = lsq[0] * (1.f / CNT2) - mean * mean;
    float rs   = rsqrtf(var + EPS_);
    float sc   = g3[c] * rs;
    float sh   = fmaf(-mean, sc, be3[c]);
    const int wv = t >> 6, l = t & 63;
    float v = lmax[wv * 64 + l];                    // tile = wv*64+l is batch wv
    #pragma unroll
    for (int off = 32; off > 0; off >>= 1) v = fmaxf(v, __shfl_xor(v, off));
    if (l == 0) out[wv * 1024 + c] = fmaf(v, sc, sh);
}

extern "C" void kernel_launch(void* const* d_in, const int* in_sizes, int n_in,
                              void* d_out, int out_size, void* d_ws, size_t ws_size,
                              hipStream_t stream) {
    const float* x   = (const float*)d_in[0];
    const float* ips = (const float*)d_in[1];
    const float* w1  = (const float*)d_in[2];
    const float* b1  = (const float*)d_in[3];
    const float* g1  = (const float*)d_in[4];
    const float* be1 = (const float*)d_in[5];
    const float* w2  = (const float*)d_in[6];
    const float* b2  = (const float*)d_in[7];
    const float* g2  = (const float*)d_in[8];
    const float* be2 = (const float*)d_in[9];
    const float* w3  = (const float*)d_in[10];
    const float* b3  = (const float*)d_in[11];
    const float* g3  = (const float*)d_in[12];
    const float* be3 = (const float*)d_in[13];
    float* out = (float*)d_out;
    float* ws  = (float*)d_ws;

    hipLaunchKernelGGL(k1_feat, dim3(1024), dim3(256), 0, stream, x, ips, w1, b1, ws);
    hipLaunchKernelGGL(k2_red1, dim3(1),    dim3(512), 0, stream, w1, b1, g1, be1, ws);
    hipLaunchKernelGGL(k3_l2,   dim3(512),  dim3(256), 0, stream, w2, b2, w3, ws);
    hipLaunchKernelGGL(k4_red2, dim3(128),  dim3(256), 0, stream, g2, be2, ws);
    hipLaunchKernelGGL(k5_l3,   dim3(256),  dim3(512), 0, stream, b3, ws);
    hipLaunchKernelGGL(k6_out,  dim3(1024), dim3(256), 0, stream, g3, be3, out, ws);
}